// Round 11
// baseline (575.715 us; speedup 1.0000x reference)
//
#include <hip/hip_runtime.h>
#include <hip/hip_bf16.h>

// B=64, C=1, H=W=1024, KS=16, F=128, OUT=10, L=4096, K=256
#define B_    64
#define F_    128
#define L_    4096
#define K_    256
#define OUT_  10
#define HW_   (1024 * 1024)
#define WIMG_ 1024
#define NL    4               // consecutive l's per block (same hb row)
#define NBLK  (L_ / NL)       // 1024 blocks

typedef __attribute__((ext_vector_type(8))) short bf16x8;   // MFMA A/B frag
typedef __attribute__((ext_vector_type(4))) float f32x4;    // MFMA C/D frag

static __device__ __forceinline__ unsigned short f2bf(float f) {
    return __builtin_bit_cast(unsigned short, __float2bfloat16(f));
}
static __device__ __forceinline__ float bf2f(unsigned short h) {
    unsigned int i = ((unsigned int)h) << 16;
    return __builtin_bit_cast(float, i);
}
static __device__ __forceinline__ ushort4 c4u(float4 v) {
    return make_ushort4(f2bf(v.x), f2bf(v.y), f2bf(v.z), f2bf(v.w));
}

// ---------------------------------------------------------------------------
// R11 = R10 + __launch_bounds__(1024, 4): VGPR budget 64 -> 128, kills the
// ~900MB scratch-spill traffic that R10's counters exposed (WRITE_SIZE 438MB).
// Structure unchanged (R10 passed validation):
//  - x: one load instr spans 4 adjacent patches -> 4 x 256B dense segments;
//       all 4 l's held in regs as bf16 (16 ushort4), staged per-l to xs.
//  - w: one load instr = one full (f,l) row = 1KB contiguous; f-half phases.
//  - wave (bq, wf): 8 MFMA per phase; epilogue ym -> fused decoder -> red.
// ---------------------------------------------------------------------------
__global__ __launch_bounds__(1024, 4)
void lcn_main(const float* __restrict__ x, const float* __restrict__ wgt,
              const float* __restrict__ bias, const float* __restrict__ dec_w,
              float* __restrict__ ws) {
    const int blk = blockIdx.x;
    const int hb  = blk >> 4;           // 0..63
    const int wq  = blk & 15;           // 4-patch chunk within image row
    const int l0  = hb * 64 + wq * NL;
    const int t    = threadIdx.x;
    const int lane = t & 63;
    const int w    = t >> 6;            // wave 0..15
    const int ln15 = lane & 15;
    const int kg   = lane >> 4;         // 0..3
    const int bq   = w >> 2;            // b-quarter (16 b's)
    const int wf   = w & 3;             // f-group within 64-f half
    const int fb   = wf * 16 + ln15;    // local f in half (0..63)
    const int bln  = bq * 16 + ln15;    // this lane's A-frag b row

    __shared__ union {
        struct { unsigned short xs[B_ * K_]; unsigned short wm[64 * K_]; } s; // 64KB
        float red[16][B_][OUT_];        // 40KB (after l-loop)
    } u;

    // ---- x loads: each instr = 4 x 256B dense segments (4 adjacent patches)
    const int xr  = lane >> 4;          // patch row-sub 0..3
    const int c4  = lane & 15;          // float4 slot across the 4 patches
    const int il  = c4 >> 2;            // which patch this lane's data is
    const int cin = (c4 & 3) * 4;       // col within patch
    ushort4 xv[16];                     // bf16: 4 b's x 4 row-groups
    {
        const float* xb = x + (size_t)(hb * 16 + xr) * WIMG_ + wq * 64 + c4 * 4;
        #pragma unroll
        for (int i = 0; i < 4; ++i)
            #pragma unroll
            for (int rg = 0; rg < 4; ++rg)
                xv[i * 4 + rg] = c4u(*reinterpret_cast<const float4*>(
                    xb + (size_t)(w * 4 + i) * HW_ + (size_t)rg * 4 * WIMG_));
    }

    float4 wg[4];
    auto WLOAD = [&](int l, int fh) {   // 1KB contiguous per instruction
        #pragma unroll
        for (int i = 0; i < 4; ++i) {
            const int f = fh * 64 + w * 4 + i;
            wg[i] = *reinterpret_cast<const float4*>(
                wgt + ((size_t)f * L_ + l) * K_ + lane * 4);
        }
    };
    auto WSTORE = [&]() {               // regs -> wm (swizzled)
        #pragma unroll
        for (int i = 0; i < 4; ++i) {
            const int fl = w * 4 + i;
            *reinterpret_cast<ushort4*>(
                &u.s.wm[fl * K_ + ((lane * 4) ^ ((fl & 7) << 3))]) = c4u(wg[i]);
        }
    };
    auto XSTORE = [&](int which) {      // lane's patch -> xs (if its turn)
        if (il == which) {
            #pragma unroll
            for (int i = 0; i < 4; ++i)
                #pragma unroll
                for (int rg = 0; rg < 4; ++rg) {
                    const int b = w * 4 + i;
                    const int k = (rg * 4 + xr) * 16 + cin;
                    *reinterpret_cast<ushort4*>(
                        &u.s.xs[b * K_ + (k ^ ((b & 7) << 3))]) = xv[i * 4 + rg];
                }
        }
    };

    // bias preload for all 4 l's (scattered dwords, done once up front)
    float bv0a[NL], bv1a[NL];
    #pragma unroll
    for (int i = 0; i < NL; ++i) {
        bv0a[i] = bias[(size_t)fb * L_ + l0 + i];
        bv1a[i] = bias[(size_t)(64 + fb) * L_ + l0 + i];
    }

    WLOAD(l0, 0);
    XSTORE(0);

    // decoder map: 32 b-pairs x 16 f-octets x 2 o-halves = 1024 (exact cover)
    const int tx5 = t & 31;             // b-pair: rows db0, db0+1
    const int tyf = (t >> 5) & 15;      // f-octet: df0..df0+7
    const int oh  = t >> 9;             // o-half
    const int db0 = tx5 * 2, df0 = tyf * 8;

    unsigned short* ym = u.s.wm;        // [64][136] bf16, overlays wm after D

    float part[2][5];
    #pragma unroll
    for (int bi = 0; bi < 2; ++bi)
        #pragma unroll
        for (int oo = 0; oo < 5; ++oo) part[bi][oo] = 0.f;

    for (int l_i = 0; l_i < NL; ++l_i) {
        const int l = l0 + l_i;
        f32x4 acc0 = (f32x4){0.f, 0.f, 0.f, 0.f};
        f32x4 acc1 = (f32x4){0.f, 0.f, 0.f, 0.f};

        WSTORE();                        // wm <- (l, f-half 0)
        WLOAD(l, 1);                     // prefetch f-half 1
        __syncthreads();                 // A: xs(l) + wm(fh0) ready

        #pragma unroll
        for (int ks = 0; ks < 8; ++ks) {
            const int kb = ks * 32 + kg * 8;
            const bf16x8 a = *reinterpret_cast<const bf16x8*>(
                &u.s.xs[bln * K_ + (kb ^ ((bln & 7) << 3))]);
            const bf16x8 bw = *reinterpret_cast<const bf16x8*>(
                &u.s.wm[fb * K_ + (kb ^ ((fb & 7) << 3))]);
            acc0 = __builtin_amdgcn_mfma_f32_16x16x32_bf16(a, bw, acc0, 0, 0, 0);
        }
        __syncthreads();                 // B: wm(fh0) reads done

        WSTORE();                        // wm <- (l, f-half 1)
        if (l_i < NL - 1) WLOAD(l + 1, 0);
        __syncthreads();                 // C: wm(fh1) ready

        #pragma unroll
        for (int ks = 0; ks < 8; ++ks) {
            const int kb = ks * 32 + kg * 8;
            const bf16x8 a = *reinterpret_cast<const bf16x8*>(
                &u.s.xs[bln * K_ + (kb ^ ((bln & 7) << 3))]);
            const bf16x8 bw = *reinterpret_cast<const bf16x8*>(
                &u.s.wm[fb * K_ + (kb ^ ((fb & 7) << 3))]);
            acc1 = __builtin_amdgcn_mfma_f32_16x16x32_bf16(a, bw, acc1, 0, 0, 0);
        }
        __syncthreads();                 // D: wm + xs reads done

        // ---- epilogue: bias + ReLU -> ym (overlays wm; safe after D) ----
        #pragma unroll
        for (int r = 0; r < 4; ++r) {
            const int b = bq * 16 + kg * 4 + r;   // C/D: row=(lane>>4)*4+reg
            ym[b * 136 + fb]      = f2bf(fmaxf(acc0[r] + bv0a[l_i], 0.f));
            ym[b * 136 + 64 + fb] = f2bf(fmaxf(acc1[r] + bv1a[l_i], 0.f));
        }
        if (l_i < NL - 1) XSTORE(l_i + 1);        // xs free after D
        __syncthreads();                 // E: ym + xs(l+1) ready

        // ---- fused decoder: accumulate part over this l ----
        bf16x8 yb0 = *reinterpret_cast<const bf16x8*>(&ym[(db0 + 0) * 136 + df0]);
        bf16x8 yb1 = *reinterpret_cast<const bf16x8*>(&ym[(db0 + 1) * 136 + df0]);
        #pragma unroll
        for (int fj = 0; fj < 8; ++fj) {
            const float y0 = bf2f((unsigned short)yb0[fj]);
            const float y1 = bf2f((unsigned short)yb1[fj]);
            #pragma unroll
            for (int oo = 0; oo < 5; ++oo) {
                const int o = oh * 5 + oo;
                const float dw = dec_w[(size_t)o * ((size_t)F_ * L_)
                                       + (size_t)(df0 + fj) * L_ + l];
                part[0][oo] = fmaf(y0, dw, part[0][oo]);
                part[1][oo] = fmaf(y1, dw, part[1][oo]);
            }
        }
        __syncthreads();                 // F: ym reads done (next WSTORE safe)
    }

    // ---- block reduction: red[16][64][10] overlays union (all LDS dead) ----
    #pragma unroll
    for (int bi = 0; bi < 2; ++bi)
        #pragma unroll
        for (int oo = 0; oo < 5; ++oo)
            u.red[tyf][db0 + bi][oh * 5 + oo] = part[bi][oo];
    __syncthreads();

    if (t < B_ * OUT_) {
        const int b = t / OUT_;
        const int o = t - b * OUT_;
        float s = 0.f;
        #pragma unroll
        for (int g = 0; g < 16; ++g) s += u.red[g][b][o];
        ws[((size_t)b * NBLK + blk) * OUT_ + o] = s;
    }
}

// ---------------------------------------------------------------------------
// Kernel B: reduce ws[b][1024][10] over chunks, add dec_b.
// ---------------------------------------------------------------------------
__global__ __launch_bounds__(640)
void lcn_reduce(const float* __restrict__ ws, const float* __restrict__ dec_b,
                float* __restrict__ out) {
    const int b = blockIdx.x;
    const int j = threadIdx.x;            // 0..639
    const float* base = ws + (size_t)b * (NBLK * OUT_);

    float s = 0.f;
    #pragma unroll 4
    for (int i = 0; i < (NBLK * OUT_) / 640; ++i)   // 16
        s += base[j + i * 640];

    __shared__ float lds[640];
    lds[j] = s;
    __syncthreads();

    if (j < OUT_) {
        float tot = dec_b[j];
        #pragma unroll
        for (int lc = 0; lc < 64; ++lc) tot += lds[lc * OUT_ + j];
        out[b * OUT_ + j] = tot;
    }
}

extern "C" void kernel_launch(void* const* d_in, const int* in_sizes, int n_in,
                              void* d_out, int out_size, void* d_ws, size_t ws_size,
                              hipStream_t stream) {
    const float* x     = (const float*)d_in[0];
    const float* wgt   = (const float*)d_in[1];
    const float* bias  = (const float*)d_in[2];
    const float* dec_w = (const float*)d_in[3];
    const float* dec_b = (const float*)d_in[4];
    float* out = (float*)d_out;
    float* wsf = (float*)d_ws;   // 64*1024*10*4 = 2.62 MB

    lcn_main<<<dim3(NBLK), dim3(1024), 0, stream>>>(x, wgt, bias, dec_w, wsf);
    lcn_reduce<<<dim3(B_), dim3(640), 0, stream>>>(wsf, dec_b, out);
}

// Round 12
// 446.637 us; speedup vs baseline: 1.2890x; 1.2890x over previous
//
#include <hip/hip_runtime.h>
#include <hip/hip_bf16.h>

// B=64, C=1, H=W=1024, KS=16, F=128, OUT=10, L=4096, K=256
#define B_    64
#define F_    128
#define L_    4096
#define K_    256
#define OUT_  10
#define HW_   (1024 * 1024)
#define WIMG_ 1024
#define NPH   8               // f-phases of 16 filters
#define WMP   260             // wm row stride (floats): 260%32=4 -> 8-sweep floor reads
#define YMP   20              // ym row stride (u16): 40B rows, b64-aligned, tiles banks

typedef __attribute__((ext_vector_type(8))) short bf16x8;   // MFMA A/B frag
typedef __attribute__((ext_vector_type(4))) float f32x4;    // MFMA C/D frag

static __device__ __forceinline__ unsigned short f2bf(float f) {
    return __builtin_bit_cast(unsigned short, __float2bfloat16(f));
}
static __device__ __forceinline__ float bf2f(unsigned short h) {
    unsigned int i = ((unsigned int)h) << 16;
    return __builtin_bit_cast(float, i);
}
static __device__ __forceinline__ bf16x8 cvt8(float4 a, float4 b) {
    bf16x8 r;
    r[0] = (short)f2bf(a.x); r[1] = (short)f2bf(a.y);
    r[2] = (short)f2bf(a.z); r[3] = (short)f2bf(a.w);
    r[4] = (short)f2bf(b.x); r[5] = (short)f2bf(b.y);
    r[6] = (short)f2bf(b.z); r[7] = (short)f2bf(b.w);
    return r;
}

// ---------------------------------------------------------------------------
// R12: no long-lived staging registers (the R10/R11 spill killer).
//  - w: __builtin_amdgcn_global_load_lds width=16 -> one full (f,l) row = 1KB
//       contiguous per wave-instruction, straight into wm[16][260] fp32
//       (padded rows; linear dest as gll requires; cvt to bf16 on read).
//       8 f-phases; phase p+1's stream issued right after the post-MFMA
//       barrier so it flows under the decoder compute.
//  - x: one-shot reg-transient stage to xs[64][256] bf16 (swizzled); x is
//       LLC-resident across replays (R8 FETCH evidence), granule less critical.
//  - 256 thr = 4 waves (wave = b-quarter); acc f32x4 per phase; ym[64][20]
//    bf16 -> fused decoder (b x f-quarter, 10 o) -> red overlay -> ws.
//  - LDS 52KB -> 3 blocks/CU; cross-block overlap hides phase serialization.
// ---------------------------------------------------------------------------
__global__ __launch_bounds__(256, 3)
void lcn_main(const float* __restrict__ x, const float* __restrict__ wgt,
              const float* __restrict__ bias, const float* __restrict__ dec_w,
              float* __restrict__ ws) {
    const int l  = blockIdx.x;
    const int hb = l >> 6, wb = l & 63;
    const int t  = threadIdx.x;
    const int lane = t & 63;
    const int wid  = t >> 6;        // 0..3 = b-quarter
    const int ln15 = lane & 15;
    const int kg   = lane >> 4;     // 0..3

    __shared__ union {
        struct {
            unsigned short xs[B_ * K_];   // 32768 B, swizzled k ^= (b&7)<<3
            float          wm[16 * WMP];  // 16640 B, one f-phase (padded rows)
            unsigned short ym[B_ * YMP];  // 2560 B, y tile of current phase
        } s;
        float red[4 * B_ * OUT_];         // 10240 B (after l-loop, overlays xs)
    } u;

    // ---- issue w phase-0 stream FIRST (async global->LDS, 1KB/instr) ----
    auto GLL = [&](int p) {
        #pragma unroll
        for (int i = 0; i < 4; ++i) {
            const int fl = wid * 4 + i;
            const float* gp = wgt + ((size_t)(p * 16 + fl) * L_ + l) * K_ + lane * 4;
            __builtin_amdgcn_global_load_lds(
                (const __attribute__((address_space(1))) void*)gp,
                (__attribute__((address_space(3))) void*)&u.s.wm[fl * WMP],
                16, 0, 0);
        }
    };
    GLL(0);

    // ---- stage x -> xs bf16 (reg-transient; 16 float4/thread) ----
    {
        const int b  = t >> 2;
        const int c4 = t & 3;
        const float* xb = x + (size_t)b * HW_ + (size_t)(hb * 16) * WIMG_
                            + wb * 16 + c4 * 4;
        const int swz = (b & 7) << 3;
        #pragma unroll
        for (int r = 0; r < 16; ++r) {
            float4 v = *reinterpret_cast<const float4*>(xb + (size_t)r * WIMG_);
            const int k = r * 16 + c4 * 4;
            *reinterpret_cast<ushort4*>(&u.s.xs[b * K_ + (k ^ swz)]) =
                make_ushort4(f2bf(v.x), f2bf(v.y), f2bf(v.z), f2bf(v.w));
        }
    }
    __syncthreads();   // xs ready; wm(0) landed (vmcnt drained at barrier)

    const int bl   = wid * 16 + ln15;     // A-frag b row
    const int xswz = (bl & 7) << 3;
    const int db   = t & 63;              // decoder: batch
    const int fq   = t >> 6;              // decoder: f-quarter of phase

    float part[OUT_];
    #pragma unroll
    for (int o = 0; o < OUT_; ++o) part[o] = 0.f;

    for (int p = 0; p < NPH; ++p) {
        // ---- MFMA: 16 f of this phase x this wave's 16 b ----
        const float bv = bias[(size_t)(p * 16 + ln15) * L_ + l];
        f32x4 acc = (f32x4){0.f, 0.f, 0.f, 0.f};
        #pragma unroll
        for (int ks = 0; ks < 8; ++ks) {
            const int kb = ks * 32 + kg * 8;
            const bf16x8 a = *reinterpret_cast<const bf16x8*>(
                &u.s.xs[bl * K_ + (kb ^ xswz)]);
            const float* wr = &u.s.wm[ln15 * WMP + kb];
            float4 w0 = *reinterpret_cast<const float4*>(wr);
            float4 w1 = *reinterpret_cast<const float4*>(wr + 4);
            const bf16x8 bw = cvt8(w0, w1);
            acc = __builtin_amdgcn_mfma_f32_16x16x32_bf16(a, bw, acc, 0, 0, 0);
        }
        // bias + ReLU -> ym (separate region; wm untouched)
        #pragma unroll
        for (int r = 0; r < 4; ++r) {
            const int b = wid * 16 + kg * 4 + r;   // C/D: row=(lane>>4)*4+reg
            u.s.ym[b * YMP + ln15] = f2bf(fmaxf(acc[r] + bv, 0.f));
        }
        __syncthreads();               // ym ready; all wm(p) reads done

        if (p + 1 < NPH) GLL(p + 1);   // next w stream flows under decoder

        // ---- fused decoder: thread (db, fq): 4 f x 10 o ----
        ushort4 yb = *reinterpret_cast<const ushort4*>(&u.s.ym[db * YMP + fq * 4]);
        const float yv0 = bf2f(yb.x), yv1 = bf2f(yb.y),
                    yv2 = bf2f(yb.z), yv3 = bf2f(yb.w);
        #pragma unroll
        for (int o = 0; o < OUT_; ++o) {
            const size_t dwbase = ((size_t)o * F_ + p * 16 + fq * 4) * L_ + l;
            float s = part[o];
            s = fmaf(yv0, dec_w[dwbase],          s);
            s = fmaf(yv1, dec_w[dwbase + L_],     s);
            s = fmaf(yv2, dec_w[dwbase + 2 * L_], s);
            s = fmaf(yv3, dec_w[dwbase + 3 * L_], s);
            part[o] = s;
        }
        __syncthreads();               // decoder done; wm(p+1) drained
    }

    // ---- reduction over the 4 f-quarters (red overlays xs; all reads done) ----
    #pragma unroll
    for (int o = 0; o < OUT_; ++o)
        u.red[(fq * B_ + db) * OUT_ + o] = part[o];
    __syncthreads();

    for (int idx = t; idx < B_ * OUT_; idx += 256) {
        const int b = idx / OUT_;
        const int o = idx - b * OUT_;
        float s = u.red[(0 * B_ + b) * OUT_ + o] + u.red[(1 * B_ + b) * OUT_ + o]
                + u.red[(2 * B_ + b) * OUT_ + o] + u.red[(3 * B_ + b) * OUT_ + o];
        ws[((size_t)b * L_ + l) * OUT_ + o] = s;
    }
}

// ---------------------------------------------------------------------------
// Kernel B: reduce ws[b][4096][10] over l, add dec_b.
// ---------------------------------------------------------------------------
__global__ __launch_bounds__(640)
void lcn_reduce(const float* __restrict__ ws, const float* __restrict__ dec_b,
                float* __restrict__ out) {
    const int b = blockIdx.x;
    const int j = threadIdx.x;            // 0..639
    const float* base = ws + (size_t)b * ((size_t)L_ * OUT_);

    float s = 0.f;
    #pragma unroll 8
    for (int i = 0; i < 64; ++i)
        s += base[j + i * (64 * OUT_)];

    __shared__ float lds[640];
    lds[j] = s;
    __syncthreads();

    if (j < OUT_) {
        float tot = dec_b[j];
        #pragma unroll
        for (int lc = 0; lc < 64; ++lc) tot += lds[lc * OUT_ + j];
        out[b * OUT_ + j] = tot;
    }
}

extern "C" void kernel_launch(void* const* d_in, const int* in_sizes, int n_in,
                              void* d_out, int out_size, void* d_ws, size_t ws_size,
                              hipStream_t stream) {
    const float* x     = (const float*)d_in[0];
    const float* wgt   = (const float*)d_in[1];
    const float* bias  = (const float*)d_in[2];
    const float* dec_w = (const float*)d_in[3];
    const float* dec_b = (const float*)d_in[4];
    float* out = (float*)d_out;
    float* wsf = (float*)d_ws;   // 64*4096*10*4 = 10.49 MB

    lcn_main<<<dim3(L_), dim3(256), 0, stream>>>(x, wgt, bias, dec_w, wsf);
    lcn_reduce<<<dim3(B_), dim3(640), 0, stream>>>(wsf, dec_b, out);
}

// Round 13
// 328.605 us; speedup vs baseline: 1.7520x; 1.3592x over previous
//
#include <hip/hip_runtime.h>
#include <hip/hip_bf16.h>

// B=64, C=1, H=W=1024, KS=16, F=128, OUT=10, L=4096, K=256
#define B_    64
#define F_    128
#define L_    4096
#define K_    256
#define OUT_  10
#define HW_   (1024 * 1024)
#define WIMG_ 1024

typedef __attribute__((ext_vector_type(8))) short bf16x8;   // MFMA A/B frag
typedef __attribute__((ext_vector_type(4))) float f32x4;    // MFMA C/D frag

static __device__ __forceinline__ unsigned short f2bf(float f) {
    return __builtin_bit_cast(unsigned short, __float2bfloat16(f));
}

// ---------------------------------------------------------------------------
// R13 = champion R8 with LDS cut 64KB -> 48KB for 3 blocks/CU (24 waves/CU):
// cross-block overlap keeps the w-stream busy through each block's phase
// barriers (the R8 residual). Only change: xs holds ONE k-half [64][128] bf16
// (16KB), staged per k-half inside the phase flow; wm[128][128] bf16 (32KB)
// k-half phases, 2x512B-contiguous-segment loads, wave map, swizzles, and
// fused epilogue are R8-identical. __launch_bounds__(512,6) pins VGPR<=85.
// ---------------------------------------------------------------------------
__global__ __launch_bounds__(512, 6)
void lcn_main(const float* __restrict__ x, const float* __restrict__ wgt,
              const float* __restrict__ bias, const float* __restrict__ dec_w,
              float* __restrict__ ws) {
    const int l  = blockIdx.x;
    const int hb = l >> 6, wb = l & 63;
    const int t  = threadIdx.x;
    const int lane = t & 63;
    const int wid  = t >> 6;        // 0..7
    const int ln15 = lane & 15;
    const int kg   = lane >> 4;     // 0..3
    const int wm2  = wid >> 2;      // b-half (0..1)
    const int wf   = wid & 3;       // f-quarter (0..3)

    __shared__ union {
        struct { unsigned short xs[B_ * 128]; unsigned short wm[F_ * 128]; } s; // 16+32 KB
        float ysm[B_][132];          // 33.8 KB (after main loop)
        float red[16][B_][OUT_];     // 40 KB   (after ysm reads)
    } u;   // 49152 B -> 3 blocks/CU

    // ---- x k-half stage: thread (b = (t>>2)&63, c4 = t&3, rh = t>>8) ----
    //      4 float4 loads (64B segments), 4 ushort4 LDS writes. Transient regs.
    const int sb  = (t >> 2) & 63;
    const int sc4 = t & 3;
    const int srh = t >> 8;             // row-quad within the k-half
    const float* xbase = x + (size_t)sb * HW_ + (size_t)(hb * 16) * WIMG_
                           + wb * 16 + sc4 * 4;
    const int sswz = (sb & 7) << 3;
    auto XSTAGE = [&](int kh) {
        #pragma unroll
        for (int i = 0; i < 4; ++i) {
            const int r = kh * 8 + srh * 4 + i;          // image row in patch
            float4 v = *reinterpret_cast<const float4*>(xbase + (size_t)r * WIMG_);
            const int kloc = (srh * 4 + i) * 16 + sc4 * 4;  // k_local in half
            *reinterpret_cast<ushort4*>(&u.s.xs[sb * 128 + (kloc ^ sswz)]) =
                make_ushort4(f2bf(v.x), f2bf(v.y), f2bf(v.z), f2bf(v.w));
        }
    };

    // ---- w k-half phase staging (R8-identical): 2x512B contiguous per instr
    const int wsf_ = wid * 16 + (lane >> 5);   // f base (i*2 added)
    const int wk4  = (lane & 31) * 4;          // k_local float offset (0..124)
    float4 wg[8];
    auto WLOAD = [&](int kh) {
        #pragma unroll
        for (int i = 0; i < 8; ++i) {
            const int f = wsf_ + i * 2;        // lanes 0-31: f, 32-63: f+1
            wg[i] = *reinterpret_cast<const float4*>(
                wgt + ((size_t)f * L_ + l) * K_ + kh * 128 + wk4);
        }
    };
    auto WSTORE = [&]() {
        #pragma unroll
        for (int i = 0; i < 8; ++i) {
            const int f = wsf_ + i * 2;
            *reinterpret_cast<ushort4*>(
                &u.s.wm[f * 128 + (wk4 ^ ((f & 7) << 3))]) =
                make_ushort4(f2bf(wg[i].x), f2bf(wg[i].y), f2bf(wg[i].z), f2bf(wg[i].w));
        }
    };

    f32x4 acc[2][2];
    #pragma unroll
    for (int m = 0; m < 2; ++m)
        #pragma unroll
        for (int n = 0; n < 2; ++n)
            acc[m][n] = (f32x4){0.f, 0.f, 0.f, 0.f};

    // ---- pipeline: [WLOAD kh0 | XSTAGE kh0] b [WSTORE kh0 | WLOAD kh1] b
    //               MFMA(kh0) b [XSTAGE kh1 | WSTORE kh1] b MFMA(kh1) ----
    WLOAD(0);
    XSTAGE(0);
    WSTORE();            // vmcnt drain for wg(0) only; xs writes already queued
    WLOAD(1);            // kh1 stream in flight across MFMA(kh0)
    __syncthreads();     // A: xs(kh0) + wm(kh0) ready

    #pragma unroll
    for (int kh = 0; kh < 2; ++kh) {
        #pragma unroll
        for (int ks = 0; ks < 4; ++ks) {
            const int kloc = ks * 32 + kg * 8;
            bf16x8 a[2], bb[2];
            #pragma unroll
            for (int m = 0; m < 2; ++m) {
                const int b = wm2 * 32 + m * 16 + ln15;
                a[m] = *reinterpret_cast<const bf16x8*>(
                    &u.s.xs[b * 128 + (kloc ^ ((b & 7) << 3))]);
            }
            #pragma unroll
            for (int n = 0; n < 2; ++n) {
                const int f = wf * 32 + n * 16 + ln15;
                bb[n] = *reinterpret_cast<const bf16x8*>(
                    &u.s.wm[f * 128 + (kloc ^ ((f & 7) << 3))]);
            }
            #pragma unroll
            for (int m = 0; m < 2; ++m)
                #pragma unroll
                for (int n = 0; n < 2; ++n)
                    acc[m][n] = __builtin_amdgcn_mfma_f32_16x16x32_bf16(
                        a[m], bb[n], acc[m][n], 0, 0, 0);
        }
        if (kh == 0) {
            __syncthreads();   // B: all kh0 reads (xs+wm) done
            XSTAGE(1);         // overwrite xs with kh1
            WSTORE();          // overwrite wm with kh1 (wg landed during MFMA)
            __syncthreads();   // C: xs(kh1) + wm(kh1) ready
        }
    }

    // ---- epilogue (R8-identical): bias + ReLU -> ysm ----
    float bv[2];
    #pragma unroll
    for (int n = 0; n < 2; ++n)
        bv[n] = bias[(size_t)(wf * 32 + n * 16 + ln15) * L_ + l];

    __syncthreads();   // D: all kh1 reads done before ysm overwrites union

    #pragma unroll
    for (int m = 0; m < 2; ++m)
        #pragma unroll
        for (int n = 0; n < 2; ++n)
            #pragma unroll
            for (int r = 0; r < 4; ++r) {
                const int b = wm2 * 32 + m * 16 + kg * 4 + r;  // C/D row map
                const int f = wf * 32 + n * 16 + ln15;         // C/D col map
                u.ysm[b][f] = fmaxf(acc[m][n][r] + bv[n], 0.f);
            }
    __syncthreads();   // E

    // ---- fused decoder (R8-identical): (oh) x (tx,ty) owns 4b x 8f ----
    const int tt = t & 255;
    const int oh = t >> 8;               // o-half: 0 -> o0..4, 1 -> o5..9
    const int tx = tt & 15, ty = tt >> 4;
    const int b0 = tx * 4, f0 = ty * 8;

    float yv[4][8];
    #pragma unroll
    for (int bi = 0; bi < 4; ++bi) {
        f32x4 p0 = *reinterpret_cast<const f32x4*>(&u.ysm[b0 + bi][f0]);
        f32x4 p1 = *reinterpret_cast<const f32x4*>(&u.ysm[b0 + bi][f0 + 4]);
        yv[bi][0] = p0.x; yv[bi][1] = p0.y; yv[bi][2] = p0.z; yv[bi][3] = p0.w;
        yv[bi][4] = p1.x; yv[bi][5] = p1.y; yv[bi][6] = p1.z; yv[bi][7] = p1.w;
    }
    __syncthreads();   // F: ysm reads done before red overwrites the union

    float part[4][5];
    #pragma unroll
    for (int bi = 0; bi < 4; ++bi)
        #pragma unroll
        for (int oo = 0; oo < 5; ++oo) part[bi][oo] = 0.f;

    #pragma unroll
    for (int fj = 0; fj < 8; ++fj) {
        #pragma unroll
        for (int oo = 0; oo < 5; ++oo) {
            const int o = oh * 5 + oo;
            const float dw = dec_w[(size_t)o * ((size_t)F_ * L_) + (size_t)(f0 + fj) * L_ + l];
            #pragma unroll
            for (int bi = 0; bi < 4; ++bi)
                part[bi][oo] = fmaf(yv[bi][fj], dw, part[bi][oo]);
        }
    }

    #pragma unroll
    for (int bi = 0; bi < 4; ++bi)
        #pragma unroll
        for (int oo = 0; oo < 5; ++oo)
            u.red[ty][b0 + bi][oh * 5 + oo] = part[bi][oo];
    __syncthreads();   // G

    for (int idx = t; idx < B_ * OUT_; idx += 512) {
        const int b = idx / OUT_;
        const int o = idx - b * OUT_;
        float s = 0.f;
        #pragma unroll
        for (int g = 0; g < 16; ++g) s += u.red[g][b][o];
        ws[((size_t)b * L_ + l) * OUT_ + o] = s;
    }
}

// ---------------------------------------------------------------------------
// Kernel B: reduce ws[b][4096][10] over l, add dec_b.
// ---------------------------------------------------------------------------
__global__ __launch_bounds__(640)
void lcn_reduce(const float* __restrict__ ws, const float* __restrict__ dec_b,
                float* __restrict__ out) {
    const int b = blockIdx.x;
    const int j = threadIdx.x;            // 0..639
    const float* base = ws + (size_t)b * ((size_t)L_ * OUT_);

    float s = 0.f;
    #pragma unroll 8
    for (int i = 0; i < 64; ++i)
        s += base[j + i * (64 * OUT_)];

    __shared__ float lds[640];
    lds[j] = s;
    __syncthreads();

    if (j < OUT_) {
        float tot = dec_b[j];
        #pragma unroll
        for (int lc = 0; lc < 64; ++lc) tot += lds[lc * OUT_ + j];
        out[b * OUT_ + j] = tot;
    }
}

extern "C" void kernel_launch(void* const* d_in, const int* in_sizes, int n_in,
                              void* d_out, int out_size, void* d_ws, size_t ws_size,
                              hipStream_t stream) {
    const float* x     = (const float*)d_in[0];
    const float* wgt   = (const float*)d_in[1];
    const float* bias  = (const float*)d_in[2];
    const float* dec_w = (const float*)d_in[3];
    const float* dec_b = (const float*)d_in[4];
    float* out = (float*)d_out;
    float* wsf = (float*)d_ws;   // 64*4096*10*4 = 10.49 MB

    lcn_main<<<dim3(L_), dim3(512), 0, stream>>>(x, wgt, bias, dec_w, wsf);
    lcn_reduce<<<dim3(B_), dim3(640), 0, stream>>>(wsf, dec_b, out);
}

// Round 14
// 264.981 us; speedup vs baseline: 2.1727x; 1.2401x over previous
//
#include <hip/hip_runtime.h>
#include <hip/hip_bf16.h>

// B=64, C=1, H=W=1024, KS=16, F=128, OUT=10, L=4096, K=256
#define B_    64
#define F_    128
#define L_    4096
#define K_    256
#define OUT_  10
#define HW_   (1024 * 1024)
#define WIMG_ 1024

typedef __attribute__((ext_vector_type(8))) short bf16x8;   // MFMA A/B frag
typedef __attribute__((ext_vector_type(4))) float f32x4;    // MFMA C/D frag

static __device__ __forceinline__ unsigned short f2bf(float f) {
    return __builtin_bit_cast(unsigned short, __float2bfloat16(f));
}

// ---------------------------------------------------------------------------
// R14: 256-thr blocks to get BOTH staging MLP and multi-block co-residency
// (the R8 vs R13 synthesis; 512-thr blocks can't have both due to the
// VGPR quantum at 64). Block = one l, all 128 f, k-half phases:
//  - LDS 48KB: xs[64][128] bf16 (16KB) + wm[128][128] bf16 (32KB), union'd
//    with ysm[64][132] f32 -> 3 blocks/CU (12 waves).
//  - staging granules = champion R8's: w 2x512B contiguous segs/instr
//    (lanes 0-31 -> f, 32-63 -> f+1); x 64B rows. Transient regs only;
//    (256,4) allows VGPR<=128 so no R13-style serialization.
//  - 4 waves (m2 = b-half, n2 = f-half): acc[2][4], 8 MFMA per k-step.
//  - decoder: thread (tx,o) owns b = tx+16*bi (interleaved: ysm reads 2-way)
//    x all 128 f; writes ws[b][l][o] directly. 5 barriers total.
// ---------------------------------------------------------------------------
__global__ __launch_bounds__(256, 4)
void lcn_main(const float* __restrict__ x, const float* __restrict__ wgt,
              const float* __restrict__ bias, const float* __restrict__ dec_w,
              float* __restrict__ ws) {
    const int l  = blockIdx.x;
    const int hb = l >> 6, wb = l & 63;
    const int t  = threadIdx.x;
    const int lane = t & 63;
    const int wid  = t >> 6;        // 0..3
    const int ln15 = lane & 15;
    const int kg   = lane >> 4;     // 0..3
    const int m2   = wid >> 1;      // b-half
    const int n2   = wid & 1;       // f-half

    __shared__ union {
        struct { unsigned short xs[B_ * 128]; unsigned short wm[F_ * 128]; } s; // 48 KB
        float ysm[B_][132];          // 33.8 KB (after main loop)
    } u;   // 49152 B -> 3 blocks/CU

    // ---- w staging: per instr 2 contiguous 512B segments (one k-half row) --
    const int lane32 = lane & 31;
    const int fhi    = lane >> 5;        // 0/1: which f of the pair
    auto WSTAGE = [&](int kh) {
        #pragma unroll
        for (int i = 0; i < 16; ++i) {
            const int f = wid * 32 + i * 2 + fhi;
            float4 v = *reinterpret_cast<const float4*>(
                wgt + ((size_t)f * L_ + l) * K_ + kh * 128 + lane32 * 4);
            *reinterpret_cast<ushort4*>(
                &u.s.wm[f * 128 + ((lane32 * 4) ^ ((f & 7) << 3))]) =
                make_ushort4(f2bf(v.x), f2bf(v.y), f2bf(v.z), f2bf(v.w));
        }
    };

    // ---- x staging: thread (b = t>>2, cq = t&3); 8 x 64B-row loads/k-half --
    const int sb  = t >> 2;
    const int scq = t & 3;
    const float* xbase = x + (size_t)sb * HW_ + (size_t)(hb * 16) * WIMG_
                           + wb * 16 + scq * 4;
    const int sswz = (sb & 7) << 3;
    auto XSTAGE = [&](int kh) {
        #pragma unroll
        for (int r = 0; r < 8; ++r) {
            float4 v = *reinterpret_cast<const float4*>(
                xbase + (size_t)(kh * 8 + r) * WIMG_);
            const int kloc = r * 16 + scq * 4;
            *reinterpret_cast<ushort4*>(&u.s.xs[sb * 128 + (kloc ^ sswz)]) =
                make_ushort4(f2bf(v.x), f2bf(v.y), f2bf(v.z), f2bf(v.w));
        }
    };

    // bias preload (4 scattered dwords, latency hidden under staging)
    float bv[4];
    #pragma unroll
    for (int n = 0; n < 4; ++n)
        bv[n] = bias[(size_t)(n2 * 64 + n * 16 + ln15) * L_ + l];

    f32x4 acc[2][4];
    #pragma unroll
    for (int m = 0; m < 2; ++m)
        #pragma unroll
        for (int n = 0; n < 4; ++n)
            acc[m][n] = (f32x4){0.f, 0.f, 0.f, 0.f};

    #pragma unroll
    for (int kh = 0; kh < 2; ++kh) {
        WSTAGE(kh);
        XSTAGE(kh);
        __syncthreads();   // S1/S3: xs(kh) + wm(kh) ready

        #pragma unroll
        for (int ks = 0; ks < 4; ++ks) {
            const int kloc = ks * 32 + kg * 8;
            bf16x8 a[2], bb[4];
            #pragma unroll
            for (int m = 0; m < 2; ++m) {
                const int b = m2 * 32 + m * 16 + ln15;
                a[m] = *reinterpret_cast<const bf16x8*>(
                    &u.s.xs[b * 128 + (kloc ^ ((b & 7) << 3))]);
            }
            #pragma unroll
            for (int n = 0; n < 4; ++n) {
                const int f = n2 * 64 + n * 16 + ln15;
                bb[n] = *reinterpret_cast<const bf16x8*>(
                    &u.s.wm[f * 128 + (kloc ^ ((f & 7) << 3))]);
            }
            #pragma unroll
            for (int m = 0; m < 2; ++m)
                #pragma unroll
                for (int n = 0; n < 4; ++n)
                    acc[m][n] = __builtin_amdgcn_mfma_f32_16x16x32_bf16(
                        a[m], bb[n], acc[m][n], 0, 0, 0);
        }
        __syncthreads();   // S2/S4: all kh reads done (restage / ysm safe)
    }

    // ---- epilogue: bias + ReLU -> ysm (overlays staging region) ----
    #pragma unroll
    for (int m = 0; m < 2; ++m)
        #pragma unroll
        for (int n = 0; n < 4; ++n)
            #pragma unroll
            for (int r = 0; r < 4; ++r) {
                const int b = m2 * 32 + m * 16 + kg * 4 + r;  // C/D row map
                const int f = n2 * 64 + n * 16 + ln15;        // C/D col map
                u.ysm[b][f] = fmaxf(acc[m][n][r] + bv[n], 0.f);
            }
    __syncthreads();       // S5: ysm ready

    // ---- fused decoder: thread (tx, o) owns b = tx + 16*bi, all 128 f ----
    if (t < 16 * OUT_) {
        const int tx = t & 15;
        const int o  = t >> 4;          // 0..9
        float part[4] = {0.f, 0.f, 0.f, 0.f};
        const float* dwp = dec_w + (size_t)o * ((size_t)F_ * L_) + l;
        #pragma unroll 8
        for (int f = 0; f < F_; ++f) {
            const float dw = dwp[(size_t)f * L_];
            #pragma unroll
            for (int bi = 0; bi < 4; ++bi)
                part[bi] = fmaf(u.ysm[tx + bi * 16][f], dw, part[bi]);
        }
        #pragma unroll
        for (int bi = 0; bi < 4; ++bi)
            ws[((size_t)(tx + bi * 16) * L_ + l) * OUT_ + o] = part[bi];
    }
}

// ---------------------------------------------------------------------------
// Kernel B: reduce ws[b][4096][10] over l, add dec_b.
// ---------------------------------------------------------------------------
__global__ __launch_bounds__(640)
void lcn_reduce(const float* __restrict__ ws, const float* __restrict__ dec_b,
                float* __restrict__ out) {
    const int b = blockIdx.x;
    const int j = threadIdx.x;            // 0..639
    const float* base = ws + (size_t)b * ((size_t)L_ * OUT_);

    float s = 0.f;
    #pragma unroll 8
    for (int i = 0; i < 64; ++i)
        s += base[j + i * (64 * OUT_)];

    __shared__ float lds[640];
    lds[j] = s;
    __syncthreads();

    if (j < OUT_) {
        float tot = dec_b[j];
        #pragma unroll
        for (int lc = 0; lc < 64; ++lc) tot += lds[lc * OUT_ + j];
        out[b * OUT_ + j] = tot;
    }
}

extern "C" void kernel_launch(void* const* d_in, const int* in_sizes, int n_in,
                              void* d_out, int out_size, void* d_ws, size_t ws_size,
                              hipStream_t stream) {
    const float* x     = (const float*)d_in[0];
    const float* wgt   = (const float*)d_in[1];
    const float* bias  = (const float*)d_in[2];
    const float* dec_w = (const float*)d_in[3];
    const float* dec_b = (const float*)d_in[4];
    float* out = (float*)d_out;
    float* wsf = (float*)d_ws;   // 64*4096*10*4 = 10.49 MB

    lcn_main<<<dim3(L_), dim3(256), 0, stream>>>(x, wgt, bias, dec_w, wsf);
    lcn_reduce<<<dim3(B_), dim3(640), 0, stream>>>(wsf, dec_b, out);
}